// Round 7
// baseline (67.642 us; speedup 1.0000x reference)
//
#include <hip/hip_runtime.h>

// CurvatureLoss: out = sum(|lap(pred) - lap(target)| * mask) / (sum(mask) + 1e-8)
// lap = 3x3 Laplacian [[0,1,0],[1,-4,1],[0,1,0]], zero ("SAME") padding.
// Linearity: lap(pred)-lap(target) == lap(pred-target).
//
// R6 = R0's LDS row-staging (best measured: 38.5us) with its three flaws fixed:
//  1. 5-slot rolling window, ONE barrier/row (write slot (r+3)%5 / read slots
//     {r,r+1,r+2}%5 are disjoint mod 5 under max wave skew -> race-free).
//  2. Loads for row r+3 issued in round r, ds_written in round r+1: every
//     global load gets a full round (barrier+compute) of slack -- the
//     decoupling all register-rolling variants (R1/R3/R5, 43-69us) lacked.
//  3. Neighbors via aligned ds_read_b128 at x4 +/- 4 into a +/-4-padded row
//     (R0's scalar stride-4-bank reads were 8-way conflicts, 786K cycles).
// Named registers only (R2/R4: arrays -> scratch). Fused last-block reduce,
// XCD-chunked swizzle.

static constexpr int IMG_W = 1024;
static constexpr int IMG_H = 1024;
static constexpr int ROWS  = 16;       // output rows per block
static constexpr int NT    = 256;      // 4 cols/thread
static constexpr int NXCD  = 8;
static constexpr int RSTR  = IMG_W + 8;        // 1032 floats/row (pad 4 each side)
static constexpr int NSLOT = 5;

__device__ __forceinline__ float4 f4z() { return make_float4(0.f, 0.f, 0.f, 0.f); }
__device__ __forceinline__ float4 f4sub(float4 a, float4 b) {
    return make_float4(a.x - b.x, a.y - b.y, a.z - b.z, a.w - b.w);
}

__global__ __launch_bounds__(NT) void curv_kernel(
    const float* __restrict__ pred,
    const float* __restrict__ target,
    const float* __restrict__ mask,
    float* __restrict__ partial,
    unsigned int* __restrict__ counter,
    float* __restrict__ out,
    int H, int nblocks)
{
    const int bid = blockIdx.x;
    const int cpx = nblocks / NXCD;
    const int wid = (bid % NXCD) * cpx + bid / NXCD;   // XCD-chunked swizzle

    const int tid  = threadIdx.x;
    const int lane = tid & 63;
    const int bpi  = H / ROWS;
    const int img  = wid / bpi;
    const int y0   = (wid % bpi) * ROWS;
    const size_t imgOff = (size_t)img * H * IMG_W;
    const int x4 = tid * 4;

    __shared__ float smem[NSLOT * RSTR];

    // Zero the pad zones of all slots once (cols -4..-1 and 1024..1027).
    if (tid < NSLOT * 4) {
        const int s = tid >> 2, c = tid & 3;
        smem[s * RSTR + c] = 0.f;
        smem[s * RSTR + 4 + IMG_W + c] = 0.f;
    }

    auto rawP = [&](int y) -> float4 {     // wave-uniform OOB -> zeros
        return (y < 0 || y >= H) ? f4z()
             : *reinterpret_cast<const float4*>(pred + imgOff + (size_t)y * IMG_W + x4);
    };
    auto rawT = [&](int y) -> float4 {
        return (y < 0 || y >= H) ? f4z()
             : *reinterpret_cast<const float4*>(target + imgOff + (size_t)y * IMG_W + x4);
    };
    auto rawM = [&](int y) -> float4 {     // only called for in-image rows
        return *reinterpret_cast<const float4*>(mask + imgOff + (size_t)y * IMG_W + x4);
    };

    // ---- Prologue: rows y0-1, y0, y0+1 into slots 0,1,2; row y0+2 in regs ----
    {
        const float4 a = f4sub(rawP(y0 - 1), rawT(y0 - 1));
        *reinterpret_cast<float4*>(&smem[0 * RSTR + 4 + x4]) = a;
        const float4 b = f4sub(rawP(y0), rawT(y0));
        *reinterpret_cast<float4*>(&smem[1 * RSTR + 4 + x4]) = b;
        const float4 c = f4sub(rawP(y0 + 1), rawT(y0 + 1));
        *reinterpret_cast<float4*>(&smem[2 * RSTR + 4 + x4]) = c;
    }
    float4 pin = rawP(y0 + 2);     // in-flight row y0+2 (named regs only)
    float4 tin = rawT(y0 + 2);
    float4 mm  = rawM(y0);         // mask row y0

    __syncthreads();

    // Rolling slot byte... (float-index) offsets: round r reads slots r,r+1,r+2,
    // writes slot (r+3)%5. Thread-uniform ints, advanced by += / wrap.
    int o_up = 0 * RSTR, o_ce = 1 * RSTR, o_dn = 2 * RSTR, o_w = 3 * RSTR;

    float lsum = 0.f, msum = 0.f;

    #pragma unroll 4
    for (int r = 0; r < ROWS; ++r) {
        // (1) ds_write row y0+r+2 (loaded last round) to slot (r+3)%5.
        if (r + 2 <= ROWS) {
            *reinterpret_cast<float4*>(&smem[o_w + 4 + x4]) = f4sub(pin, tin);
        }
        // (2) issue loads for row y0+r+3 (landed by next round's write).
        if (r + 3 <= ROWS) { pin = rawP(y0 + r + 3); tin = rawT(y0 + r + 3); }
        // (3) mask for next round (always in-image: y0+r+1 <= y0+ROWS-1).
        float4 mnext = f4z();
        if (r + 1 < ROWS) mnext = rawM(y0 + r + 1);

        __syncthreads();

        // (4) compute row y0+r from slots o_up/o_ce/o_dn (all aligned b128).
        const float4 du = *reinterpret_cast<const float4*>(&smem[o_up + 4 + x4]);
        const float4 cl = *reinterpret_cast<const float4*>(&smem[o_ce + x4]);      // cols x4-4..x4-1
        const float4 cc = *reinterpret_cast<const float4*>(&smem[o_ce + 4 + x4]);
        const float4 cr = *reinterpret_cast<const float4*>(&smem[o_ce + 8 + x4]);  // cols x4+4..x4+7
        const float4 dd = *reinterpret_cast<const float4*>(&smem[o_dn + 4 + x4]);

        const float l0 = du.x + dd.x + cl.w + cc.y - 4.f * cc.x;
        const float l1 = du.y + dd.y + cc.x + cc.z - 4.f * cc.y;
        const float l2 = du.z + dd.z + cc.y + cc.w - 4.f * cc.z;
        const float l3 = du.w + dd.w + cc.z + cr.x - 4.f * cc.w;

        lsum += fabsf(l0) * mm.x + fabsf(l1) * mm.y + fabsf(l2) * mm.z + fabsf(l3) * mm.w;
        msum += mm.x + mm.y + mm.z + mm.w;

        mm = mnext;
        o_up = o_ce; o_ce = o_dn; o_dn = o_w;
        o_w += RSTR; if (o_w >= NSLOT * RSTR) o_w = 0;
    }

    // ---- Block reduction ----
    for (int off = 32; off > 0; off >>= 1) {
        lsum += __shfl_down(lsum, off, 64);
        msum += __shfl_down(msum, off, 64);
    }
    __shared__ float wls[NT / 64], wms[NT / 64];
    __shared__ unsigned int s_ticket;
    const int wave = tid >> 6;
    if (lane == 0) { wls[wave] = lsum; wms[wave] = msum; }
    __syncthreads();
    if (tid == 0) {
        float L = 0.f, Mm = 0.f;
        #pragma unroll
        for (int w = 0; w < NT / 64; ++w) { L += wls[w]; Mm += wms[w]; }
        __hip_atomic_store(&partial[2 * (size_t)wid],     L,  __ATOMIC_RELAXED, __HIP_MEMORY_SCOPE_AGENT);
        __hip_atomic_store(&partial[2 * (size_t)wid + 1], Mm, __ATOMIC_RELAXED, __HIP_MEMORY_SCOPE_AGENT);
        __threadfence();
        s_ticket = atomicAdd(counter, 1u);
    }
    __syncthreads();

    // ---- Last block reduces all partials (deterministic order) ----
    if (s_ticket == (unsigned int)(nblocks - 1)) {
        __threadfence();
        float L = 0.f, Mm = 0.f;
        for (int i = tid; i < nblocks; i += NT) {
            L  += __hip_atomic_load(&partial[2 * (size_t)i],     __ATOMIC_RELAXED, __HIP_MEMORY_SCOPE_AGENT);
            Mm += __hip_atomic_load(&partial[2 * (size_t)i + 1], __ATOMIC_RELAXED, __HIP_MEMORY_SCOPE_AGENT);
        }
        for (int off = 32; off > 0; off >>= 1) {
            L  += __shfl_down(L, off, 64);
            Mm += __shfl_down(Mm, off, 64);
        }
        if (lane == 0) { wls[wave] = L; wms[wave] = Mm; }
        __syncthreads();
        if (tid == 0) {
            float LL = 0.f, MM = 0.f;
            #pragma unroll
            for (int w = 0; w < NT / 64; ++w) { LL += wls[w]; MM += wms[w]; }
            out[0] = LL / (MM + 1e-8f);
        }
    }
}

extern "C" void kernel_launch(void* const* d_in, const int* in_sizes, int n_in,
                              void* d_out, int out_size, void* d_ws, size_t ws_size,
                              hipStream_t stream) {
    const float* pred   = (const float*)d_in[0];
    const float* target = (const float*)d_in[1];
    const float* mask   = (const float*)d_in[2];
    float* out = (float*)d_out;

    const int H = IMG_H;
    const int B = in_sizes[0] / (IMG_H * IMG_W);
    const int nblocks = B * (H / ROWS);        // 1024

    float* partial = (float*)d_ws;
    unsigned int* counter = (unsigned int*)((char*)d_ws + 16384);

    hipMemsetAsync(counter, 0, sizeof(unsigned int), stream);
    curv_kernel<<<nblocks, NT, 0, stream>>>(pred, target, mask, partial, counter, out, H, nblocks);
}

// Round 8
// 40.564 us; speedup vs baseline: 1.6675x; 1.6675x over previous
//
#include <hip/hip_runtime.h>

// CurvatureLoss: out = sum(|lap(pred) - lap(target)| * mask) / (sum(mask) + 1e-8)
// lap = 3x3 Laplacian [[0,1,0],[1,-4,1],[0,1,0]], zero ("SAME") padding.
// Linearity: lap(pred)-lap(target) == lap(pred-target).
//
// R7 = R6's pipelined 5-slot LDS loop + R0's plain two-kernel reduction tail.
// Attribution test: R3/R5/R6 (wildly different loops, same fused-reduce tail)
// all timed 66-69us; R0/R1 (no tail) timed 38.5/43.6. Hypothesis: the tail's
// 1024x { __threadfence (agent fence -> L2 writeback on non-coherent-XCD
// CDNA4) + device-scope atomicAdd on ONE contended line } costs ~25-30us.
// So: NO atomics, NO fences, NO memset, NO swizzle. Partials via plain
// stores; end-of-kernel release + next-kernel acquire gives visibility.

static constexpr int IMG_W = 1024;
static constexpr int IMG_H = 1024;
static constexpr int ROWS  = 16;       // output rows per block
static constexpr int NT    = 256;      // 4 cols/thread
static constexpr int RSTR  = IMG_W + 8;        // 1032 floats/row (pad 4 each side)
static constexpr int NSLOT = 5;

__device__ __forceinline__ float4 f4z() { return make_float4(0.f, 0.f, 0.f, 0.f); }
__device__ __forceinline__ float4 f4sub(float4 a, float4 b) {
    return make_float4(a.x - b.x, a.y - b.y, a.z - b.z, a.w - b.w);
}

__global__ __launch_bounds__(NT) void curv_partial_kernel(
    const float* __restrict__ pred,
    const float* __restrict__ target,
    const float* __restrict__ mask,
    float* __restrict__ partial,       // [2 * gridDim.x]
    int H)
{
    const int bid  = blockIdx.x;
    const int tid  = threadIdx.x;
    const int lane = tid & 63;
    const int bpi  = H / ROWS;
    const int img  = bid / bpi;
    const int y0   = (bid % bpi) * ROWS;
    const size_t imgOff = (size_t)img * H * IMG_W;
    const int x4 = tid * 4;

    __shared__ float smem[NSLOT * RSTR];

    // Zero the pad zones of all slots once (cols -4..-1 and 1024..1027).
    if (tid < NSLOT * 4) {
        const int s = tid >> 2, c = tid & 3;
        smem[s * RSTR + c] = 0.f;
        smem[s * RSTR + 4 + IMG_W + c] = 0.f;
    }

    auto rawP = [&](int y) -> float4 {     // wave-uniform OOB -> zeros
        return (y < 0 || y >= H) ? f4z()
             : *reinterpret_cast<const float4*>(pred + imgOff + (size_t)y * IMG_W + x4);
    };
    auto rawT = [&](int y) -> float4 {
        return (y < 0 || y >= H) ? f4z()
             : *reinterpret_cast<const float4*>(target + imgOff + (size_t)y * IMG_W + x4);
    };
    auto rawM = [&](int y) -> float4 {     // only called for in-image rows
        return *reinterpret_cast<const float4*>(mask + imgOff + (size_t)y * IMG_W + x4);
    };

    // ---- Prologue: rows y0-1, y0, y0+1 into slots 0,1,2; row y0+2 in regs ----
    {
        const float4 a = f4sub(rawP(y0 - 1), rawT(y0 - 1));
        *reinterpret_cast<float4*>(&smem[0 * RSTR + 4 + x4]) = a;
        const float4 b = f4sub(rawP(y0), rawT(y0));
        *reinterpret_cast<float4*>(&smem[1 * RSTR + 4 + x4]) = b;
        const float4 c = f4sub(rawP(y0 + 1), rawT(y0 + 1));
        *reinterpret_cast<float4*>(&smem[2 * RSTR + 4 + x4]) = c;
    }
    float4 pin = rawP(y0 + 2);     // in-flight row y0+2 (named regs only)
    float4 tin = rawT(y0 + 2);
    float4 mm  = rawM(y0);         // mask row y0

    __syncthreads();

    // Round r: write slot (r+3)%5 (row r+2, loaded last round), issue loads for
    // row r+3, ONE barrier, compute row r from slots {r,r+1,r+2}%5. Write/read
    // slots stay disjoint mod 5 under max wave skew -> race-free.
    int o_up = 0 * RSTR, o_ce = 1 * RSTR, o_dn = 2 * RSTR, o_w = 3 * RSTR;

    float lsum = 0.f, msum = 0.f;

    #pragma unroll 4
    for (int r = 0; r < ROWS; ++r) {
        // (1) ds_write row y0+r+2 (loaded LAST round -> vmcnt long since clear).
        if (r + 2 <= ROWS) {
            *reinterpret_cast<float4*>(&smem[o_w + 4 + x4]) = f4sub(pin, tin);
        }
        // (2) issue loads for row y0+r+3 (a full round of slack to land).
        if (r + 3 <= ROWS) { pin = rawP(y0 + r + 3); tin = rawT(y0 + r + 3); }
        // (3) mask for next round.
        float4 mnext = f4z();
        if (r + 1 < ROWS) mnext = rawM(y0 + r + 1);

        __syncthreads();

        // (4) compute row y0+r (all aligned b128 LDS reads into padded rows).
        const float4 du = *reinterpret_cast<const float4*>(&smem[o_up + 4 + x4]);
        const float4 cl = *reinterpret_cast<const float4*>(&smem[o_ce + x4]);      // cols x4-4..-1
        const float4 cc = *reinterpret_cast<const float4*>(&smem[o_ce + 4 + x4]);
        const float4 cr = *reinterpret_cast<const float4*>(&smem[o_ce + 8 + x4]);  // cols x4+4..+7
        const float4 dd = *reinterpret_cast<const float4*>(&smem[o_dn + 4 + x4]);

        const float l0 = du.x + dd.x + cl.w + cc.y - 4.f * cc.x;
        const float l1 = du.y + dd.y + cc.x + cc.z - 4.f * cc.y;
        const float l2 = du.z + dd.z + cc.y + cc.w - 4.f * cc.z;
        const float l3 = du.w + dd.w + cc.z + cr.x - 4.f * cc.w;

        lsum += fabsf(l0) * mm.x + fabsf(l1) * mm.y + fabsf(l2) * mm.z + fabsf(l3) * mm.w;
        msum += mm.x + mm.y + mm.z + mm.w;

        mm = mnext;
        o_up = o_ce; o_ce = o_dn; o_dn = o_w;
        o_w += RSTR; if (o_w >= NSLOT * RSTR) o_w = 0;
    }

    // ---- Block reduction (plain stores, no atomics/fences) ----
    for (int off = 32; off > 0; off >>= 1) {
        lsum += __shfl_down(lsum, off, 64);
        msum += __shfl_down(msum, off, 64);
    }
    __shared__ float wls[NT / 64], wms[NT / 64];
    const int wave = tid >> 6;
    if (lane == 0) { wls[wave] = lsum; wms[wave] = msum; }
    __syncthreads();
    if (tid == 0) {
        float L = 0.f, M = 0.f;
        #pragma unroll
        for (int w = 0; w < NT / 64; ++w) { L += wls[w]; M += wms[w]; }
        partial[2 * (size_t)bid]     = L;
        partial[2 * (size_t)bid + 1] = M;
    }
}

__global__ __launch_bounds__(256) void curv_final_kernel(
    const float* __restrict__ partial, float* __restrict__ out, int nblocks)
{
    __shared__ float sL[256], sM[256];
    float L = 0.f, M = 0.f;
    for (int i = threadIdx.x; i < nblocks; i += 256) {
        L += partial[2 * (size_t)i];
        M += partial[2 * (size_t)i + 1];
    }
    sL[threadIdx.x] = L; sM[threadIdx.x] = M;
    __syncthreads();
    for (int s = 128; s > 0; s >>= 1) {
        if (threadIdx.x < s) {
            sL[threadIdx.x] += sL[threadIdx.x + s];
            sM[threadIdx.x] += sM[threadIdx.x + s];
        }
        __syncthreads();
    }
    if (threadIdx.x == 0) out[0] = sL[0] / (sM[0] + 1e-8f);
}

extern "C" void kernel_launch(void* const* d_in, const int* in_sizes, int n_in,
                              void* d_out, int out_size, void* d_ws, size_t ws_size,
                              hipStream_t stream) {
    const float* pred   = (const float*)d_in[0];
    const float* target = (const float*)d_in[1];
    const float* mask   = (const float*)d_in[2];
    float* out = (float*)d_out;
    float* partial = (float*)d_ws;

    const int H = IMG_H;
    const int B = in_sizes[0] / (IMG_H * IMG_W);
    const int nblocks = B * (H / ROWS);        // 1024

    curv_partial_kernel<<<nblocks, NT, 0, stream>>>(pred, target, mask, partial, H);
    curv_final_kernel<<<1, 256, 0, stream>>>(partial, out, nblocks);
}

// Round 9
// 37.739 us; speedup vs baseline: 1.7923x; 1.0748x over previous
//
#include <hip/hip_runtime.h>

// CurvatureLoss: out = sum(|lap(pred) - lap(target)| * mask) / (sum(mask) + 1e-8)
// lap = 3x3 Laplacian [[0,1,0],[1,-4,1],[0,1,0]], zero ("SAME") padding.
// Linearity: lap(pred)-lap(target) == lap(pred-target).
//
// R9 = R0 verbatim (best measured: 38.5us timed; 2-barrier LDS rolling window,
// scalar LDS neighbor reads, plain two-kernel reduction tail) + XCD-chunked
// block swizzle (adjacent strips share halo rows -> same XCD L2). Single
// variable vs R0.
//
// Session findings driving this: (1) fused atomic+fence tail costs ~27us
// (R3/R5/R6 vs R7); (2) register-rolling variants lose 5-30us to exposed
// per-row load latency (R1/R3/R5); (3) per-thread state arrays -> scratch
// (R2: 167MB, R4: 277MB WRITE_SIZE); (4) LDS bank conflicts at this
// intensity are duration-neutral (R7: 7M cycles, same time); (5) three
// unrelated loop structures converge at ~5.9-6.4 TB/s effective = the
// m13 achievable-BW ceiling -> memory roofline.

static constexpr int IMG_W = 1024;   // fixed by reference
static constexpr int IMG_H = 1024;   // fixed by reference
static constexpr int TH_ROWS = 16;   // output rows per block
static constexpr int NT = 256;       // threads per block (4 cols/thread at W=1024)
static constexpr int NXCD = 8;

__global__ __launch_bounds__(NT) void curv_partial_kernel(
    const float* __restrict__ pred,
    const float* __restrict__ target,
    const float* __restrict__ mask,
    float* __restrict__ partial,   // [2 * gridDim.x]: (loss_sum, mask_sum) per block
    int H, int nblocks)
{
    __shared__ float sd[3][IMG_W];     // rotating 3-row window of d = pred - target
    __shared__ float wls[NT / 64], wms[NT / 64];

    // XCD-chunked swizzle: consecutive work ids (adjacent strips, sharing halo
    // rows) execute on the same XCD's L2. nblocks % 8 == 0 (1024).
    const int cpx = nblocks / NXCD;
    const int wid = (blockIdx.x % NXCD) * cpx + blockIdx.x / NXCD;

    const int tid = threadIdx.x;
    const int blocksPerImage = H / TH_ROWS;
    const int b  = wid / blocksPerImage;
    const int y0 = (wid % blocksPerImage) * TH_ROWS;
    const size_t imgOff = (size_t)b * H * IMG_W;
    const int x4 = tid * 4;            // this thread's 4 columns

    float lsum = 0.f, msum = 0.f;

    auto loadRow = [&](int y, int slot) {
        float4 d;
        if (y >= 0 && y < H) {
            const size_t o = imgOff + (size_t)y * IMG_W + x4;
            const float4 p = *reinterpret_cast<const float4*>(pred + o);
            const float4 t = *reinterpret_cast<const float4*>(target + o);
            d = make_float4(p.x - t.x, p.y - t.y, p.z - t.z, p.w - t.w);
        } else {
            d = make_float4(0.f, 0.f, 0.f, 0.f);  // zero padding rows
        }
        *reinterpret_cast<float4*>(&sd[slot][x4]) = d;
    };

    // Prime the window: rows y0-1 and y0.
    loadRow(y0 - 1, 0);
    loadRow(y0,     1);

    for (int r = 0; r < TH_ROWS; ++r) {
        const int y = y0 + r;
        loadRow(y + 1, (r + 2) % 3);
        __syncthreads();

        const float* up = sd[r % 3];
        const float* ce = sd[(r + 1) % 3];
        const float* dn = sd[(r + 2) % 3];

        const float4 m = *reinterpret_cast<const float4*>(mask + imgOff + (size_t)y * IMG_W + x4);

        const float c0 = ce[x4], c1 = ce[x4 + 1], c2 = ce[x4 + 2], c3 = ce[x4 + 3];
        const float left  = (x4 == 0)         ? 0.f : ce[x4 - 1];
        const float right = (x4 + 4 == IMG_W) ? 0.f : ce[x4 + 4];

        const float l0 = up[x4]     + dn[x4]     + left + c1    - 4.f * c0;
        const float l1 = up[x4 + 1] + dn[x4 + 1] + c0   + c2    - 4.f * c1;
        const float l2 = up[x4 + 2] + dn[x4 + 2] + c1   + c3    - 4.f * c2;
        const float l3 = up[x4 + 3] + dn[x4 + 3] + c2   + right - 4.f * c3;

        lsum += fabsf(l0) * m.x + fabsf(l1) * m.y + fabsf(l2) * m.z + fabsf(l3) * m.w;
        msum += m.x + m.y + m.z + m.w;

        __syncthreads();  // before next iteration overwrites the 'up' slot
    }

    // Wave (64-lane) butterfly reduce, then cross-wave via LDS.
    for (int off = 32; off > 0; off >>= 1) {
        lsum += __shfl_down(lsum, off, 64);
        msum += __shfl_down(msum, off, 64);
    }
    const int wave = tid >> 6;
    if ((tid & 63) == 0) { wls[wave] = lsum; wms[wave] = msum; }
    __syncthreads();
    if (tid == 0) {
        float L = 0.f, M = 0.f;
        #pragma unroll
        for (int w = 0; w < NT / 64; ++w) { L += wls[w]; M += wms[w]; }
        partial[2 * (size_t)wid]     = L;
        partial[2 * (size_t)wid + 1] = M;
    }
}

__global__ __launch_bounds__(256) void curv_final_kernel(
    const float* __restrict__ partial, float* __restrict__ out, int nblocks)
{
    __shared__ float sL[256], sM[256];
    float L = 0.f, M = 0.f;
    for (int i = threadIdx.x; i < nblocks; i += 256) {
        L += partial[2 * (size_t)i];
        M += partial[2 * (size_t)i + 1];
    }
    sL[threadIdx.x] = L; sM[threadIdx.x] = M;
    __syncthreads();
    for (int s = 128; s > 0; s >>= 1) {
        if (threadIdx.x < s) {
            sL[threadIdx.x] += sL[threadIdx.x + s];
            sM[threadIdx.x] += sM[threadIdx.x + s];
        }
        __syncthreads();
    }
    if (threadIdx.x == 0) out[0] = sL[0] / (sM[0] + 1e-8f);
}

extern "C" void kernel_launch(void* const* d_in, const int* in_sizes, int n_in,
                              void* d_out, int out_size, void* d_ws, size_t ws_size,
                              hipStream_t stream) {
    const float* pred   = (const float*)d_in[0];
    const float* target = (const float*)d_in[1];
    const float* mask   = (const float*)d_in[2];
    float* out = (float*)d_out;
    float* partial = (float*)d_ws;

    const int H = IMG_H;
    const int B = in_sizes[0] / (IMG_H * IMG_W);
    const int nblocks = B * (H / TH_ROWS);   // 16 * 64 = 1024

    curv_partial_kernel<<<nblocks, NT, 0, stream>>>(pred, target, mask, partial, H, nblocks);
    curv_final_kernel<<<1, 256, 0, stream>>>(partial, out, nblocks);
}